// Round 2
// baseline (1302.989 us; speedup 1.0000x reference)
//
#include <hip/hip_runtime.h>
#include <math.h>

#define N_ROWS 16384
#define K_CODES 4096
#define D_DIM 512
#define NCHUNK 8          // K split into 8 chunks of 512 cols
#define KCHUNK (K_CODES / NCHUNK)

__device__ __forceinline__ float fmul_(float a, float b) { return __fmul_rn(a, b); }
__device__ __forceinline__ float fadd_(float a, float b) { return __fadd_rn(a, b); }

// ---------------------------------------------------------------- kernel 1
// Bit-exact emulation of np.sum(x*x, axis=1) for rows of length 512.
// numpy pairwise_sum(512) = (B0+B1)+(B2+B3), each Bi over 128 elems with
// 8 accumulators r[j]+=a[8i+j] (sequential i), combined
// ((r0+r1)+(r2+r3))+((r4+r5)+(r6+r7)).  4 lanes per row (one 128-block each).
__global__ void rownorm_np_kernel(const float* __restrict__ src, int nrows,
                                  float* __restrict__ out) {
    int gid = blockIdx.x * blockDim.x + threadIdx.x;
    int row = gid >> 2;
    int blk = gid & 3;
    if (row >= nrows) return;
    const float4* p = (const float4*)(src + (size_t)row * D_DIM + blk * 128);
    float4 v0 = p[0], v1 = p[1];
    float r0 = fmul_(v0.x, v0.x), r1 = fmul_(v0.y, v0.y);
    float r2 = fmul_(v0.z, v0.z), r3 = fmul_(v0.w, v0.w);
    float r4 = fmul_(v1.x, v1.x), r5 = fmul_(v1.y, v1.y);
    float r6 = fmul_(v1.z, v1.z), r7 = fmul_(v1.w, v1.w);
#pragma unroll
    for (int i = 1; i < 16; i++) {
        float4 w0 = p[2 * i], w1 = p[2 * i + 1];
        r0 = fadd_(r0, fmul_(w0.x, w0.x));
        r1 = fadd_(r1, fmul_(w0.y, w0.y));
        r2 = fadd_(r2, fmul_(w0.z, w0.z));
        r3 = fadd_(r3, fmul_(w0.w, w0.w));
        r4 = fadd_(r4, fmul_(w1.x, w1.x));
        r5 = fadd_(r5, fmul_(w1.y, w1.y));
        r6 = fadd_(r6, fmul_(w1.z, w1.z));
        r7 = fadd_(r7, fmul_(w1.w, w1.w));
    }
    float s = fadd_(fadd_(fadd_(r0, r1), fadd_(r2, r3)),
                    fadd_(fadd_(r4, r5), fadd_(r6, r7)));
    // combine blocks: (s0+s1)+(s2+s3)
    float u = __shfl_down(s, 1, 64);
    float t = fadd_(s, u);           // valid on blk 0 (s0+s1) and blk 2 (s2+s3)
    float w = __shfl_down(t, 2, 64);
    float tot = fadd_(t, w);         // valid on blk 0
    if (blk == 0) out[row] = tot;
}

// ---------------------------------------------------------------- kernel 2
// Fused fp32 GEMM + numpy-fp32-emulated dist + per-chunk first-occurrence
// argmin.  dist = fl32( fl32(zz_n + cc_k) - 2*dot )  via single-rounding fmaf.
#define BM 128
#define BN 128
#define BK 16
#define TM 8
#define TN 8

__global__ __launch_bounds__(256, 4) void vq_argmin_kernel(
    const float* __restrict__ z, const float* __restrict__ cb,
    const float* __restrict__ zz, const float* __restrict__ cnorm,
    float* __restrict__ pval, int* __restrict__ pidx) {
    __shared__ float As[BK][BM + 4];
    __shared__ float Bs[BK][BN + 4];
    __shared__ float rv[BM][17];
    __shared__ int   ri[BM][17];

    const int bx = blockIdx.x;            // k-chunk 0..7
    const int by = blockIdx.y;            // row tile 0..127
    const int row0 = by * BM;
    const int k0 = bx * KCHUNK;
    const int t = threadIdx.x;
    const int tx = t & 15;
    const int ty = t >> 4;

    float minv[TM];
    int   mini[TM];
#pragma unroll
    for (int i = 0; i < TM; i++) { minv[i] = 3.4e38f; mini[i] = 0; }

    float zrow[TM];
#pragma unroll
    for (int i = 0; i < TM; i++) zrow[i] = zz[row0 + ty * TM + i];

    const int sr = t >> 1;            // 0..127
    const int sdq = (t & 1) * 8;      // 0 or 8

    for (int kt = 0; kt < KCHUNK / BN; kt++) {
        const int col0 = k0 + kt * BN;
        float acc[TM][TN];
#pragma unroll
        for (int i = 0; i < TM; i++)
#pragma unroll
            for (int j = 0; j < TN; j++) acc[i][j] = 0.f;

        for (int dt = 0; dt < D_DIM; dt += BK) {
            {
                const float* src = z + (size_t)(row0 + sr) * D_DIM + dt + sdq;
                float4 v0 = *(const float4*)(src);
                float4 v1 = *(const float4*)(src + 4);
                As[sdq + 0][sr] = v0.x; As[sdq + 1][sr] = v0.y;
                As[sdq + 2][sr] = v0.z; As[sdq + 3][sr] = v0.w;
                As[sdq + 4][sr] = v1.x; As[sdq + 5][sr] = v1.y;
                As[sdq + 6][sr] = v1.z; As[sdq + 7][sr] = v1.w;
                const float* srcb = cb + (size_t)(col0 + sr) * D_DIM + dt + sdq;
                float4 w0 = *(const float4*)(srcb);
                float4 w1 = *(const float4*)(srcb + 4);
                Bs[sdq + 0][sr] = w0.x; Bs[sdq + 1][sr] = w0.y;
                Bs[sdq + 2][sr] = w0.z; Bs[sdq + 3][sr] = w0.w;
                Bs[sdq + 4][sr] = w1.x; Bs[sdq + 5][sr] = w1.y;
                Bs[sdq + 6][sr] = w1.z; Bs[sdq + 7][sr] = w1.w;
            }
            __syncthreads();
#pragma unroll
            for (int d = 0; d < BK; d++) {
                float a[TM], b[TN];
#pragma unroll
                for (int i = 0; i < TM; i++) a[i] = As[d][ty * TM + i];
#pragma unroll
                for (int j = 0; j < TN; j++) b[j] = Bs[d][tx * TN + j];
#pragma unroll
                for (int i = 0; i < TM; i++)
#pragma unroll
                    for (int j = 0; j < TN; j++)
                        acc[i][j] = fmaf(a[i], b[j], acc[i][j]);
            }
            __syncthreads();
        }
        // epilogue: dist = fl( fl(zz+cc) - 2*dot ), running first-occurrence min
#pragma unroll
        for (int j = 0; j < TN; j++) {
            const int col = col0 + tx * TN + j;
            const float cn = cnorm[col];
#pragma unroll
            for (int i = 0; i < TM; i++) {
                float s1 = fadd_(zrow[i], cn);          // fl32(zz_n + cc_k)
                float s = fmaf(-2.f, acc[i][j], s1);    // fl32(s1 - 2*M), single rounding
                if (s < minv[i]) { minv[i] = s; mini[i] = col; }
            }
        }
    }

#pragma unroll
    for (int i = 0; i < TM; i++) {
        rv[ty * TM + i][tx] = minv[i];
        ri[ty * TM + i][tx] = mini[i];
    }
    __syncthreads();
    if (t < BM) {
        float bv = rv[t][0];
        int   bi = ri[t][0];
#pragma unroll
        for (int x = 1; x < 16; x++) {
            float v = rv[t][x]; int ii = ri[t][x];
            if (v < bv || (v == bv && ii < bi)) { bv = v; bi = ii; }
        }
        pval[(size_t)(row0 + t) * NCHUNK + bx] = bv;
        pidx[(size_t)(row0 + t) * NCHUNK + bx] = bi;
    }
}

// ---------------------------------------------------------------- kernel 3
__global__ void finalize_kernel(const float* __restrict__ z,
                                const float* __restrict__ cb,
                                const float* __restrict__ pval,
                                const int* __restrict__ pidx,
                                float* __restrict__ out_zq,
                                float* __restrict__ out_idx,
                                float* __restrict__ rowsum) {
    int row = (blockIdx.x * blockDim.x + threadIdx.x) >> 6;
    int lane = threadIdx.x & 63;
    if (row >= N_ROWS) return;
    float bv = pval[(size_t)row * NCHUNK];
    int   bi = pidx[(size_t)row * NCHUNK];
#pragma unroll
    for (int c = 1; c < NCHUNK; c++) {
        float v = pval[(size_t)row * NCHUNK + c];
        int  ii = pidx[(size_t)row * NCHUNK + c];
        if (v < bv || (v == bv && ii < bi)) { bv = v; bi = ii; }
    }
    const float4* zr = (const float4*)(z + (size_t)row * D_DIM);
    const float4* cr = (const float4*)(cb + (size_t)bi * D_DIM);
    float4* orow = (float4*)(out_zq + (size_t)row * D_DIM);
    float s = 0.f;
#pragma unroll
    for (int i = 0; i < 2; i++) {
        float4 zv = zr[i * 64 + lane];
        float4 cv = cr[i * 64 + lane];
        float4 o;
        // replicate fp32: z + (z_q - z), no contraction/simplification
        o.x = fadd_(zv.x, __fsub_rn(cv.x, zv.x));
        o.y = fadd_(zv.y, __fsub_rn(cv.y, zv.y));
        o.z = fadd_(zv.z, __fsub_rn(cv.z, zv.z));
        o.w = fadd_(zv.w, __fsub_rn(cv.w, zv.w));
        orow[i * 64 + lane] = o;
        float dx = zv.x - cv.x, dy = zv.y - cv.y;
        float dz = zv.z - cv.z, dw = zv.w - cv.w;
        s += dx * dx + dy * dy + dz * dz + dw * dw;
    }
#pragma unroll
    for (int off = 32; off; off >>= 1) s += __shfl_down(s, off, 64);
    if (lane == 0) {
        rowsum[row] = s;
        out_idx[row] = (float)bi;
    }
}

// ---------------------------------------------------------------- kernel 4
__global__ void loss_kernel(const float* __restrict__ rowsum,
                            float* __restrict__ out_loss) {
    __shared__ float sm[256];
    float s = 0.f;
    for (int i = threadIdx.x; i < N_ROWS; i += 256) s += rowsum[i];
    sm[threadIdx.x] = s;
    __syncthreads();
    for (int st = 128; st; st >>= 1) {
        if (threadIdx.x < st) sm[threadIdx.x] += sm[threadIdx.x + st];
        __syncthreads();
    }
    if (threadIdx.x == 0)
        *out_loss = 1.25f * sm[0] / (float)(N_ROWS * D_DIM);
}

// ---------------------------------------------------------------- launch
extern "C" void kernel_launch(void* const* d_in, const int* in_sizes, int n_in,
                              void* d_out, int out_size, void* d_ws, size_t ws_size,
                              hipStream_t stream) {
    const float* z  = (const float*)d_in[0];
    const float* cb = (const float*)d_in[1];
    float* out      = (float*)d_out;
    float* out_zq   = out;
    float* out_idx  = out + (size_t)N_ROWS * D_DIM;
    float* out_loss = out_idx + N_ROWS;

    float* zz     = (float*)d_ws;
    float* cnorm  = zz + N_ROWS;
    float* pval   = cnorm + K_CODES;
    int*   pidx   = (int*)(pval + (size_t)N_ROWS * NCHUNK);
    float* rowsum = (float*)(pidx + (size_t)N_ROWS * NCHUNK);

    rownorm_np_kernel<<<(N_ROWS * 4) / 256, 256, 0, stream>>>(z, N_ROWS, zz);
    rownorm_np_kernel<<<(K_CODES * 4) / 256, 256, 0, stream>>>(cb, K_CODES, cnorm);

    dim3 g2(NCHUNK, N_ROWS / BM);
    vq_argmin_kernel<<<g2, 256, 0, stream>>>(z, cb, zz, cnorm, pval, pidx);

    finalize_kernel<<<N_ROWS / 4, 256, 0, stream>>>(z, cb, pval, pidx,
                                                    out_zq, out_idx, rowsum);
    loss_kernel<<<1, 256, 0, stream>>>(rowsum, out_loss);
}